// Round 9
// baseline (141.863 us; speedup 1.0000x reference)
//
#include <hip/hip_runtime.h>
#include <hip/hip_bf16.h>

#define VOCAB 100000
#define EMBED 64
#define NPAIR (1024 * 50)   // B*S (51200)
#define KIDS  20
#define NSLICE 4
#define SLICE_ROWS (VOCAB / NSLICE)   // 25000 rows = 3.2 MB bf16 < 4 MB L2

typedef int int4v __attribute__((ext_vector_type(4)));

static __device__ inline ushort f2bf(float f) {
    __hip_bfloat16 h = __float2bfloat16(f);   // RN conversion
    return __builtin_bit_cast(ushort, h);
}
static __device__ inline float bf2f(ushort u) {
    unsigned int v = ((unsigned int)u) << 16;  // exact widening
    return __builtin_bit_cast(float, v);
}

// ---------------------------------------------------------------------------
// Kernel 1: transpose+convert W [E=64, V] fp32 -> Wt [V, E=64] bf16 (12.8 MB).
// W read once -> nontemporal. Wt writes stay cached (gather reads them).
// ---------------------------------------------------------------------------
__global__ __launch_bounds__(256) void convert_w(const float* __restrict__ W,
                                                 ushort* __restrict__ Wt) {
    __shared__ float tile[64][65];   // +1 pad
    const int v0 = blockIdx.x * 64;
    const int tx = threadIdx.x & 63;   // v offset within tile
    const int ty = threadIdx.x >> 6;   // 0..3
    const int v = v0 + tx;
    if (v < VOCAB) {
        #pragma unroll
        for (int e = ty; e < 64; e += 4) {
            tile[tx][e] = __builtin_nontemporal_load(&W[(size_t)e * VOCAB + v]);
        }
    }
    __syncthreads();
    const int r  = threadIdx.x >> 2;          // v offset within tile
    const int c0 = (threadIdx.x & 3) * 16;    // e base
    if (v0 + r < VOCAB) {
        uint pk[8];
        #pragma unroll
        for (int i = 0; i < 8; i++) {
            ushort lo = f2bf(tile[r][c0 + 2 * i + 0]);
            ushort hi = f2bf(tile[r][c0 + 2 * i + 1]);
            pk[i] = (uint)lo | ((uint)hi << 16);
        }
        uint4* outv = (uint4*)(Wt + (size_t)(v0 + r) * 64 + c0);
        outv[0] = make_uint4(pk[0], pk[1], pk[2], pk[3]);
        outv[1] = make_uint4(pk[4], pk[5], pk[6], pk[7]);
    }
}

// ---------------------------------------------------------------------------
// Kernel 2: R3 gather structure + vocab-slice temporal herding.
// One wave per (b,s) pair; lane = embed dim; 20 coalesced 128B row loads.
// The 20 gathers are reordered into 4 vocab-range passes (3.2 MB each) so
// the GPU-wide instantaneous working set fits every XCD's 4 MB L2.
// Ids are wave-uniform -> readfirstlane to SGPRs: scalar range checks,
// scalar-based gather addresses. Same bytes/lines as R3, different order.
// ---------------------------------------------------------------------------
__global__ __launch_bounds__(256) void gather_herd(const int* __restrict__ ids,
                                                   const ushort* __restrict__ Wt,
                                                   const float* __restrict__ bias,
                                                   float* __restrict__ out) {
    const int wave = (blockIdx.x * blockDim.x + threadIdx.x) >> 6;
    const int lane = threadIdx.x & 63;
    if (wave >= NPAIR) return;

    // 20 ids = 5 x int4, wave-uniform address (broadcast), stream-once.
    const int4v* idv = (const int4v*)(ids + (size_t)wave * KIDS);
    int4v q0 = __builtin_nontemporal_load(&idv[0]);
    int4v q1 = __builtin_nontemporal_load(&idv[1]);
    int4v q2 = __builtin_nontemporal_load(&idv[2]);
    int4v q3 = __builtin_nontemporal_load(&idv[3]);
    int4v q4 = __builtin_nontemporal_load(&idv[4]);

    // Hoist wave-uniform ids to SGPRs.
    int sid[KIDS];
    sid[0]  = __builtin_amdgcn_readfirstlane(q0.x);
    sid[1]  = __builtin_amdgcn_readfirstlane(q0.y);
    sid[2]  = __builtin_amdgcn_readfirstlane(q0.z);
    sid[3]  = __builtin_amdgcn_readfirstlane(q0.w);
    sid[4]  = __builtin_amdgcn_readfirstlane(q1.x);
    sid[5]  = __builtin_amdgcn_readfirstlane(q1.y);
    sid[6]  = __builtin_amdgcn_readfirstlane(q1.z);
    sid[7]  = __builtin_amdgcn_readfirstlane(q1.w);
    sid[8]  = __builtin_amdgcn_readfirstlane(q2.x);
    sid[9]  = __builtin_amdgcn_readfirstlane(q2.y);
    sid[10] = __builtin_amdgcn_readfirstlane(q2.z);
    sid[11] = __builtin_amdgcn_readfirstlane(q2.w);
    sid[12] = __builtin_amdgcn_readfirstlane(q3.x);
    sid[13] = __builtin_amdgcn_readfirstlane(q3.y);
    sid[14] = __builtin_amdgcn_readfirstlane(q3.z);
    sid[15] = __builtin_amdgcn_readfirstlane(q3.w);
    sid[16] = __builtin_amdgcn_readfirstlane(q4.x);
    sid[17] = __builtin_amdgcn_readfirstlane(q4.y);
    sid[18] = __builtin_amdgcn_readfirstlane(q4.z);
    sid[19] = __builtin_amdgcn_readfirstlane(q4.w);

    float acc = bias[lane];
    // Herded passes: all waves sweep vocab slices in the same order.
    #pragma unroll
    for (int s = 0; s < NSLICE; s++) {
        const int lo = s * SLICE_ROWS;
        const int hi = lo + SLICE_ROWS;
        #pragma unroll
        for (int k = 0; k < KIDS; k++) {
            if (sid[k] >= lo && sid[k] < hi) {   // scalar branch (uniform)
                acc += bf2f(Wt[((uint)sid[k] << 6) + lane]);
            }
        }
    }
    __builtin_nontemporal_store(acc, &out[(size_t)wave * 64 + lane]);
}

// ---------------------------------------------------------------------------
// Fallback (ws too small): direct uncoalesced gather on native W [E, V].
// ---------------------------------------------------------------------------
__global__ __launch_bounds__(256) void gather_direct(const int* __restrict__ ids,
                                                     const float* __restrict__ W,
                                                     const float* __restrict__ bias,
                                                     float* __restrict__ out) {
    const int wave = (blockIdx.x * blockDim.x + threadIdx.x) >> 6;
    const int lane = threadIdx.x & 63;
    if (wave >= NPAIR) return;

    const int* myids = ids + (size_t)wave * KIDS;
    float acc = bias[lane];
    #pragma unroll
    for (int k = 0; k < KIDS; k++) {
        int id = myids[k];
        acc += W[(size_t)lane * VOCAB + id];
    }
    out[(size_t)wave * 64 + lane] = acc;
}

extern "C" void kernel_launch(void* const* d_in, const int* in_sizes, int n_in,
                              void* d_out, int out_size, void* d_ws, size_t ws_size,
                              hipStream_t stream) {
    const int*   ids  = (const int*)d_in[0];    // [B,S,K] int32
    const float* W    = (const float*)d_in[1];  // [E, V] fp32
    const float* bias = (const float*)d_in[2];  // [E] fp32
    float*       out  = (float*)d_out;          // [B,S,E] fp32

    const size_t wt_bytes = (size_t)VOCAB * EMBED * sizeof(ushort);  // 12.8 MB

    if (ws_size >= wt_bytes) {
        ushort* Wt = (ushort*)d_ws;
        const int tr_blocks = (VOCAB + 63) / 64;           // 1563
        convert_w<<<tr_blocks, 256, 0, stream>>>(W, Wt);
        const int g_blocks = (NPAIR * 64 + 255) / 256;     // 12800
        gather_herd<<<g_blocks, 256, 0, stream>>>(ids, Wt, bias, out);
    } else {
        const int g_blocks = (NPAIR * 64 + 255) / 256;
        gather_direct<<<g_blocks, 256, 0, stream>>>(ids, W, bias, out);
    }
}